// Round 3
// baseline (885.825 us; speedup 1.0000x reference)
//
#include <hip/hip_runtime.h>
#include <cstdint>
#include <cstddef>

// Problem constants
#define B_    512
#define N_    128
#define C_    256
#define H_    8
#define WSZ   16
#define HD    32
#define NW    8
#define M_TOT 65536   // B_*N_

typedef __bf16 bf16x8 __attribute__((ext_vector_type(8)));
typedef float  f32x4  __attribute__((ext_vector_type(4)));
typedef unsigned short u16;
typedef unsigned int   u32;

__device__ __forceinline__ float bf2f(u16 v){
  union { u32 u; float f; } c; c.u = ((u32)v) << 16; return c.f;
}
__device__ __forceinline__ u16 f2bf(float f){
  union { float f; u32 u; } c; c.f = f;
  return (u16)((c.u + 0x7FFFu + ((c.u >> 16) & 1u)) >> 16);  // RNE
}

__device__ __forceinline__ void gload_lds16(const void* g, void* l){
  __builtin_amdgcn_global_load_lds(
      (const __attribute__((address_space(1))) u32*)g,
      (__attribute__((address_space(3))) u32*)l, 16, 0, 0);
}

__device__ __forceinline__ void unpack8(uint4 r, float* d){
  d[0]=bf2f((u16)(r.x & 0xFFFFu)); d[1]=bf2f((u16)(r.x >> 16));
  d[2]=bf2f((u16)(r.y & 0xFFFFu)); d[3]=bf2f((u16)(r.y >> 16));
  d[4]=bf2f((u16)(r.z & 0xFFFFu)); d[5]=bf2f((u16)(r.z >> 16));
  d[6]=bf2f((u16)(r.w & 0xFFFFu)); d[7]=bf2f((u16)(r.w >> 16));
}

// ---------------- LayerNorm (+ roll by -shift) -> bf16 ----------------
__global__ __launch_bounds__(256) void ln_kernel(const float* __restrict__ x,
    const float* __restrict__ g, const float* __restrict__ b,
    u16* __restrict__ out, int shift)
{
  int lane = threadIdx.x & 63;
  int row  = blockIdx.x * 4 + (threadIdx.x >> 6);
  int in_row = (row & ~(N_-1)) | ((row + shift) & (N_-1));
  float4 xv = *reinterpret_cast<const float4*>(x + (size_t)in_row * C_ + lane * 4);
  float s  = xv.x + xv.y + xv.z + xv.w;
  float s2 = xv.x*xv.x + xv.y*xv.y + xv.z*xv.z + xv.w*xv.w;
  #pragma unroll
  for (int off = 1; off < 64; off <<= 1){ s += __shfl_xor(s, off); s2 += __shfl_xor(s2, off); }
  float mean = s * (1.f / C_);
  float inv  = rsqrtf(s2 * (1.f / C_) - mean * mean + 1e-5f);
  float4 gv = *reinterpret_cast<const float4*>(g + lane * 4);
  float4 bv = *reinterpret_cast<const float4*>(b + lane * 4);
  ushort4 o;
  o.x = f2bf((xv.x - mean) * inv * gv.x + bv.x);
  o.y = f2bf((xv.y - mean) * inv * gv.y + bv.y);
  o.z = f2bf((xv.z - mean) * inv * gv.z + bv.z);
  o.w = f2bf((xv.w - mean) * inv * gv.w + bv.w);
  *reinterpret_cast<ushort4*>(out + (size_t)row * C_ + lane * 4) = o;
}

// ---------------- weight cast f32 -> bf16 ----------------
__global__ __launch_bounds__(256) void cvt_kernel(const float* __restrict__ s,
                                                  u16* __restrict__ d, int n4)
{
  int i = blockIdx.x * 256 + threadIdx.x;
  if (i >= n4) return;
  float4 v = reinterpret_cast<const float4*>(s)[i];
  ushort4 o; o.x=f2bf(v.x); o.y=f2bf(v.y); o.z=f2bf(v.z); o.w=f2bf(v.w);
  reinterpret_cast<ushort4*>(d)[i] = o;
}

// ---------------- GEMM: out[m][n] = A[m][:] . W[n][:] + bias[n] (+epilogue) --------
// A: M x K bf16 row-major, W: N x K bf16 row-major (NT GEMM).
// EPI 0: bf16 store (qkv) | 1: exact GELU + bf16 (fc1)
// EPI 2: roll(+shift) + residual, f32 (proj) | 3: residual, f32 (fc2)
// 128x128 tile, BK=64, 4 waves 2x2, DOUBLE-BUFFERED LDS with next-tile
// prefetch issued BEFORE current-tile compute (T3 2-phase minimum recipe):
// global_load_lds latency overlaps MFMA instead of serializing per K-step.
template<int EPI, int K>
__global__ __launch_bounds__(256) void gemm_kernel(const u16* __restrict__ A,
    const u16* __restrict__ W, const float* __restrict__ bias,
    u16* __restrict__ outb, float* __restrict__ outf, const float* __restrict__ resid,
    int Nout, int shift)
{
  __shared__ __align__(16) u16 Al[2][128 * 64];
  __shared__ __align__(16) u16 Bl[2][128 * 64];
  int lane = threadIdx.x & 63, wv = threadIdx.x >> 6;
  int wm = (wv >> 1) * 64, wn = (wv & 1) * 64;
  size_t Abase = (size_t)blockIdx.x * 128 * K;
  size_t Wbase = (size_t)blockIdx.y * 128 * K;

  f32x4 acc[4][4];
  #pragma unroll
  for (int mi = 0; mi < 4; mi++)
    #pragma unroll
    for (int ni = 0; ni < 4; ni++)
      #pragma unroll
      for (int r = 0; r < 4; r++) acc[mi][ni][r] = 0.f;

  int r0 = wv * 32;                 // this wave stages rows [r0, r0+32)
  int srow = lane >> 3, skc = (lane & 7) * 8;

  auto STAGE = [&](int buf, int kt){
    #pragma unroll
    for (int t = 0; t < 4; t++){
      int row = r0 + t * 8 + srow;
      gload_lds16(A + Abase + (size_t)row * K + kt + skc, &Al[buf][(r0 + t * 8) * 64]);
      gload_lds16(W + Wbase + (size_t)row * K + kt + skc, &Bl[buf][(r0 + t * 8) * 64]);
    }
  };
  auto COMPUTE = [&](int buf){
    #pragma unroll
    for (int kk = 0; kk < 64; kk += 32){
      int ko = kk + (lane >> 4) * 8;
      bf16x8 af[4], bfr[4];
      #pragma unroll
      for (int mi = 0; mi < 4; mi++)
        af[mi] = *reinterpret_cast<const bf16x8*>(&Al[buf][(wm + mi * 16 + (lane & 15)) * 64 + ko]);
      #pragma unroll
      for (int ni = 0; ni < 4; ni++)
        bfr[ni] = *reinterpret_cast<const bf16x8*>(&Bl[buf][(wn + ni * 16 + (lane & 15)) * 64 + ko]);
      #pragma unroll
      for (int mi = 0; mi < 4; mi++)
        #pragma unroll
        for (int ni = 0; ni < 4; ni++)
          acc[mi][ni] = __builtin_amdgcn_mfma_f32_16x16x32_bf16(af[mi], bfr[ni], acc[mi][ni], 0, 0, 0);
    }
  };

  constexpr int NT = K / 64;
  STAGE(0, 0);
  __syncthreads();                    // tile 0 resident
  int cur = 0;
  #pragma unroll
  for (int t = 0; t < NT - 1; ++t){
    STAGE(cur ^ 1, (t + 1) * 64);     // issue next-tile loads FIRST
    COMPUTE(cur);                     // MFMA hides the load latency
    __syncthreads();                  // drains vmcnt -> next tile resident
    cur ^= 1;
  }
  COMPUTE(cur);                       // epilogue tile, no prefetch

  // C/D layout: col = lane&15, row = (lane>>4)*4 + reg
  int col0 = blockIdx.y * 128 + wn + (lane & 15);
  float bv[4];
  #pragma unroll
  for (int ni = 0; ni < 4; ni++) bv[ni] = bias[col0 + ni * 16];
  int rbase = blockIdx.x * 128 + wm + (lane >> 4) * 4;
  #pragma unroll
  for (int mi = 0; mi < 4; mi++){
    #pragma unroll
    for (int r = 0; r < 4; r++){
      int m = rbase + mi * 16 + r;
      #pragma unroll
      for (int ni = 0; ni < 4; ni++){
        float v = acc[mi][ni][r] + bv[ni];
        int n = col0 + ni * 16;
        if (EPI == 0){
          outb[(size_t)m * Nout + n] = f2bf(v);
        } else if (EPI == 1){
          v = 0.5f * v * (1.f + erff(v * 0.70710678118654752f));
          outb[(size_t)m * Nout + n] = f2bf(v);
        } else if (EPI == 2){
          size_t idx = (size_t)((m & ~(N_-1)) | ((m + shift) & (N_-1))) * Nout + n;
          outf[idx] = v + resid[idx];     // same-element read->write: safe if aliased
        } else {
          size_t idx = (size_t)m * Nout + n;
          outf[idx] = v + resid[idx];
        }
      }
    }
  }
}

// ---------------- windowed attention (one block/window-group, one wave/head) -------
// qkv row-major [rows][768]: q at col h*32+d, k at 256+h*32+d, v at 512+h*32+d.
// LDS rows padded to 36 floats (144B, 16B-aligned) so K/V inner loops read float4.
__global__ __launch_bounds__(512) void attn_kernel(const u16* __restrict__ qkv,
    const float* __restrict__ rb, u16* __restrict__ o, int shifted)
{
  __shared__ float q_s[H_][WSZ][36];
  __shared__ float k_s[H_][WSZ][36];
  __shared__ float v_s[H_][WSZ][36];
  __shared__ float p_s[H_][WSZ][17];
  int h = threadIdx.x >> 6, lane = threadIdx.x & 63;
  int i = lane >> 2, c8 = (lane & 3) * 8;
  int m0 = blockIdx.x * WSZ;
  size_t base = (size_t)(m0 + i) * 768 + h * HD + c8;
  uint4 rq = *reinterpret_cast<const uint4*>(qkv + base);
  uint4 rk = *reinterpret_cast<const uint4*>(qkv + base + 256);
  uint4 rv = *reinterpret_cast<const uint4*>(qkv + base + 512);
  unpack8(rq, &q_s[h][i][c8]);
  unpack8(rk, &k_s[h][i][c8]);
  unpack8(rv, &v_s[h][i][c8]);
  __syncthreads();

  float qv[HD];
  #pragma unroll
  for (int d4 = 0; d4 < 8; d4++){
    float4 t = *reinterpret_cast<const float4*>(&q_s[h][i][d4 * 4]);
    qv[d4*4+0] = t.x; qv[d4*4+1] = t.y; qv[d4*4+2] = t.z; qv[d4*4+3] = t.w;
  }

  int j0 = (lane & 3) * 4;
  bool lastw = shifted && ((blockIdx.x & (NW - 1)) == NW - 1);
  float p[4];
  #pragma unroll
  for (int jj = 0; jj < 4; jj++){
    int j = j0 + jj;
    float d = 0.f;
    #pragma unroll
    for (int d4 = 0; d4 < 8; d4++){
      float4 kv = *reinterpret_cast<const float4*>(&k_s[h][j][d4 * 4]);
      d += qv[d4*4+0]*kv.x + qv[d4*4+1]*kv.y + qv[d4*4+2]*kv.z + qv[d4*4+3]*kv.w;
    }
    d *= 0.17677669529663689f;          // HD^-0.5
    d += rb[(15 + i - j) * H_ + h];     // relative position bias
    if (lastw && ((i < 8) != (j < 8))) d -= 100.f;  // swin shift mask (window 7)
    p[jj] = d;
  }
  // softmax over 16 cols: row i lives on a 4-lane group, 4 vals each
  float mx = fmaxf(fmaxf(p[0], p[1]), fmaxf(p[2], p[3]));
  mx = fmaxf(mx, __shfl_xor(mx, 1));
  mx = fmaxf(mx, __shfl_xor(mx, 2));
  float sum = 0.f;
  #pragma unroll
  for (int jj = 0; jj < 4; jj++){ p[jj] = expf(p[jj] - mx); sum += p[jj]; }
  sum += __shfl_xor(sum, 1);
  sum += __shfl_xor(sum, 2);
  float inv = 1.f / sum;
  #pragma unroll
  for (int jj = 0; jj < 4; jj++) p_s[h][i][j0 + jj] = p[jj] * inv;
  __syncthreads();

  float4 a0 = {0.f,0.f,0.f,0.f}, a1 = {0.f,0.f,0.f,0.f};
  #pragma unroll
  for (int j = 0; j < WSZ; j++){
    float pv = p_s[h][i][j];
    float4 v0 = *reinterpret_cast<const float4*>(&v_s[h][j][c8]);
    float4 v1 = *reinterpret_cast<const float4*>(&v_s[h][j][c8 + 4]);
    a0.x += pv*v0.x; a0.y += pv*v0.y; a0.z += pv*v0.z; a0.w += pv*v0.w;
    a1.x += pv*v1.x; a1.y += pv*v1.y; a1.z += pv*v1.z; a1.w += pv*v1.w;
  }
  uint4 w;
  w.x = (u32)f2bf(a0.x) | ((u32)f2bf(a0.y) << 16);
  w.y = (u32)f2bf(a0.z) | ((u32)f2bf(a0.w) << 16);
  w.z = (u32)f2bf(a1.x) | ((u32)f2bf(a1.y) << 16);
  w.w = (u32)f2bf(a1.z) | ((u32)f2bf(a1.w) << 16);
  *reinterpret_cast<uint4*>(o + (size_t)(m0 + i) * C_ + h * HD + c8) = w;
}

// ---------------- launch ----------------
// ws_size = 256 MiB (observed via harness 0xAA fill of 2.685e8 B). Full-M,
// un-chunked. Layout (peak 164 MB):
//   [0,3M)      bf16 weights
//   [4,36M)     h / h2 bf16 (65536x256)
//   [36,132M)   qkv bf16 (65536x768)   } u (65536x1024, 128MB) reuses [36,164M)
//   [132,164M)  attn-out bf16          }   after o is dead
extern "C" void kernel_launch(void* const* d_in, const int* in_sizes, int n_in,
                              void* d_out, int out_size, void* d_ws, size_t ws_size,
                              hipStream_t stream)
{
  const float* x      = (const float*)d_in[0];
  const float* ln1_g  = (const float*)d_in[1];
  const float* ln1_b  = (const float*)d_in[2];
  const float* qkv_w  = (const float*)d_in[3];
  const float* qkv_b  = (const float*)d_in[4];
  const float* proj_w = (const float*)d_in[5];
  const float* proj_b = (const float*)d_in[6];
  const float* rel_b  = (const float*)d_in[7];
  const float* ln2_g  = (const float*)d_in[8];
  const float* ln2_b  = (const float*)d_in[9];
  const float* fc1_w  = (const float*)d_in[10];
  const float* fc1_b  = (const float*)d_in[11];
  const float* fc2_w  = (const float*)d_in[12];
  const float* fc2_b  = (const float*)d_in[13];
  float* out = (float*)d_out;
  char*  ws  = (char*)d_ws;

  u16* qkv_wb  = (u16*)ws;                 // 393216 elems
  u16* proj_wb = qkv_wb + 393216;          // 131072
  u16* fc1_wb  = proj_wb + 131072;         // 524288
  u16* fc2_wb  = fc1_wb + 524288;          // 524288  (ends at 3 MB)
  u16* h_buf   = (u16*)(ws + (  4ull << 20));
  u16* qkv_buf = (u16*)(ws + ( 36ull << 20));
  u16* o_buf   = (u16*)(ws + (132ull << 20));
  u16* h2_buf  = h_buf;
  u16* u_buf   = qkv_buf;

  cvt_kernel<<<384, 256, 0, stream>>>(qkv_w,  qkv_wb,  393216 / 4);
  cvt_kernel<<<128, 256, 0, stream>>>(proj_w, proj_wb, 131072 / 4);
  cvt_kernel<<<512, 256, 0, stream>>>(fc1_w,  fc1_wb,  524288 / 4);
  cvt_kernel<<<512, 256, 0, stream>>>(fc2_w,  fc2_wb,  524288 / 4);

  const float* xin = x;
  for (int d = 0; d < 2; d++){
    int shift = d ? (WSZ / 2) : 0;
    // LN1 + roll(-shift) -> h (bf16)
    ln_kernel<<<M_TOT / 4, 256, 0, stream>>>(xin, ln1_g + d * C_, ln1_b + d * C_,
        h_buf, shift);
    // QKV: 65536x256 @ (768x256)^T
    gemm_kernel<0, 256><<<dim3(512, 6), 256, 0, stream>>>(h_buf, qkv_wb + d * 196608,
        qkv_b + d * 768, qkv_buf, nullptr, nullptr, 768, 0);
    // windowed attention -> o (bf16, rolled order)
    attn_kernel<<<M_TOT / WSZ, 512, 0, stream>>>(qkv_buf, rel_b + d * 248, o_buf,
        shift ? 1 : 0);
    // proj + roll(+shift) + residual -> x1 (d_out, fp32)
    gemm_kernel<2, 256><<<dim3(512, 2), 256, 0, stream>>>(o_buf, proj_wb + d * 65536,
        proj_b + d * C_, nullptr, out, xin, C_, shift);
    // LN2 -> h2 (bf16)
    ln_kernel<<<M_TOT / 4, 256, 0, stream>>>(out, ln2_g + d * C_, ln2_b + d * C_,
        h2_buf, 0);
    // FC1 + GELU -> u (bf16)
    gemm_kernel<1, 256><<<dim3(512, 8), 256, 0, stream>>>(h2_buf, fc1_wb + d * 262144,
        fc1_b + d * 1024, u_buf, nullptr, nullptr, 1024, 0);
    // FC2 + residual -> d_out (fp32)
    gemm_kernel<3, 1024><<<dim3(512, 2), 256, 0, stream>>>(u_buf, fc2_wb + d * 262144,
        fc2_b + d * C_, nullptr, out, out, C_, 0);
    xin = out;
  }
}

// Round 4
// 693.858 us; speedup vs baseline: 1.2767x; 1.2767x over previous
//
#include <hip/hip_runtime.h>
#include <cstdint>
#include <cstddef>

// Problem constants
#define B_    512
#define N_    128
#define C_    256
#define H_    8
#define WSZ   16
#define HD    32
#define NW    8
#define M_TOT 65536   // B_*N_

typedef __bf16 bf16x8 __attribute__((ext_vector_type(8)));
typedef float  f32x4  __attribute__((ext_vector_type(4)));
typedef unsigned short u16;
typedef unsigned int   u32;

__device__ __forceinline__ float bf2f(u16 v){
  union { u32 u; float f; } c; c.u = ((u32)v) << 16; return c.f;
}
__device__ __forceinline__ u16 f2bf(float f){
  union { float f; u32 u; } c; c.f = f;
  return (u16)((c.u + 0x7FFFu + ((c.u >> 16) & 1u)) >> 16);  // RNE
}

__device__ __forceinline__ void gload_lds16(const void* g, void* l){
  __builtin_amdgcn_global_load_lds(
      (const __attribute__((address_space(1))) u32*)g,
      (__attribute__((address_space(3))) u32*)l, 16, 0, 0);
}

__device__ __forceinline__ void unpack8(uint4 r, float* d){
  d[0]=bf2f((u16)(r.x & 0xFFFFu)); d[1]=bf2f((u16)(r.x >> 16));
  d[2]=bf2f((u16)(r.y & 0xFFFFu)); d[3]=bf2f((u16)(r.y >> 16));
  d[4]=bf2f((u16)(r.z & 0xFFFFu)); d[5]=bf2f((u16)(r.z >> 16));
  d[6]=bf2f((u16)(r.w & 0xFFFFu)); d[7]=bf2f((u16)(r.w >> 16));
}

// ---------------- LayerNorm (+ roll by -shift) -> bf16 ----------------
__global__ __launch_bounds__(256) void ln_kernel(const float* __restrict__ x,
    const float* __restrict__ g, const float* __restrict__ b,
    u16* __restrict__ out, int shift)
{
  int lane = threadIdx.x & 63;
  int row  = blockIdx.x * 4 + (threadIdx.x >> 6);
  int in_row = (row & ~(N_-1)) | ((row + shift) & (N_-1));
  float4 xv = *reinterpret_cast<const float4*>(x + (size_t)in_row * C_ + lane * 4);
  float s  = xv.x + xv.y + xv.z + xv.w;
  float s2 = xv.x*xv.x + xv.y*xv.y + xv.z*xv.z + xv.w*xv.w;
  #pragma unroll
  for (int off = 1; off < 64; off <<= 1){ s += __shfl_xor(s, off); s2 += __shfl_xor(s2, off); }
  float mean = s * (1.f / C_);
  float inv  = rsqrtf(s2 * (1.f / C_) - mean * mean + 1e-5f);
  float4 gv = *reinterpret_cast<const float4*>(g + lane * 4);
  float4 bv = *reinterpret_cast<const float4*>(b + lane * 4);
  ushort4 o;
  o.x = f2bf((xv.x - mean) * inv * gv.x + bv.x);
  o.y = f2bf((xv.y - mean) * inv * gv.y + bv.y);
  o.z = f2bf((xv.z - mean) * inv * gv.z + bv.z);
  o.w = f2bf((xv.w - mean) * inv * gv.w + bv.w);
  *reinterpret_cast<ushort4*>(out + (size_t)row * C_ + lane * 4) = o;
}

// ---------------- weight cast f32 -> bf16 ----------------
__global__ __launch_bounds__(256) void cvt_kernel(const float* __restrict__ s,
                                                  u16* __restrict__ d, int n4)
{
  int i = blockIdx.x * 256 + threadIdx.x;
  if (i >= n4) return;
  float4 v = reinterpret_cast<const float4*>(s)[i];
  ushort4 o; o.x=f2bf(v.x); o.y=f2bf(v.y); o.z=f2bf(v.z); o.w=f2bf(v.w);
  reinterpret_cast<ushort4*>(d)[i] = o;
}

// ---------------- GEMM: out[m][n] = A[m][:] . W[n][:] + bias[n] (+epilogue) --------
// A: M x K bf16 row-major, W: N x K bf16 row-major (NT GEMM).
// EPI 0: bf16 store (qkv) | 1: exact GELU + bf16 (fc1)
// EPI 2: roll(+shift) + residual, f32 (proj) | 3: residual, f32 (fc2)
// 128x128 tile, BK=64, 4 waves 2x2, single-buffered 32KB LDS (5 blocks/CU).
// T2 both-sides XOR swizzle: global source chunk pre-swizzled per lane
// ((lane&7)^(lane>>3)) so linear global_load_lds dest yields swizzled layout;
// fragment reads use phys_chunk = j ^ (row&7) -> 2-way banks (free).
// T1 XCD-chunked 1-D grid, n-fastest within chunk (A-panel L2 reuse per XCD).
template<int EPI, int K, int NN>
__global__ __launch_bounds__(256) void gemm_kernel(const u16* __restrict__ A,
    const u16* __restrict__ W, const float* __restrict__ bias,
    u16* __restrict__ outb, float* __restrict__ outf, const float* __restrict__ resid,
    int Nout, int shift)
{
  __shared__ __align__(16) u16 Al[128 * 64];
  __shared__ __align__(16) u16 Bl[128 * 64];
  int lane = threadIdx.x & 63, wv = threadIdx.x >> 6;
  int wm = (wv >> 1) * 64, wn = (wv & 1) * 64;

  // XCD-chunked swizzle (gridDim.x % 8 == 0 for all shapes here), n-fastest
  int nwg = gridDim.x;
  int nid = (blockIdx.x & 7) * (nwg >> 3) + (blockIdx.x >> 3);
  int bm = nid / NN, bn = nid % NN;

  size_t Abase = (size_t)bm * 128 * K;
  size_t Wbase = (size_t)bn * 128 * K;

  f32x4 acc[4][4];
  #pragma unroll
  for (int mi = 0; mi < 4; mi++)
    #pragma unroll
    for (int ni = 0; ni < 4; ni++)
      #pragma unroll
      for (int r = 0; r < 4; r++) acc[mi][ni][r] = 0.f;

  int r0 = wv * 32;                 // this wave stages rows [r0, r0+32)
  int srow = lane >> 3;
  int scol = ((lane & 7) ^ (lane >> 3)) * 8;   // pre-swizzled global chunk

  for (int kt = 0; kt < K; kt += 64){
    __syncthreads();                // readers done with previous tile
    #pragma unroll
    for (int t = 0; t < 4; t++){
      int row = r0 + t * 8 + srow;
      gload_lds16(A + Abase + (size_t)row * K + kt + scol, &Al[(r0 + t * 8) * 64]);
      gload_lds16(W + Wbase + (size_t)row * K + kt + scol, &Bl[(r0 + t * 8) * 64]);
    }
    __syncthreads();                // drains vmcnt -> staged data visible
    #pragma unroll
    for (int kk = 0; kk < 64; kk += 32){
      int j = (kk >> 3) + (lane >> 4);             // logical 16B chunk
      int ko = ((j ^ (lane & 7)) << 3);            // swizzled LDS offset (elems)
      bf16x8 af[4], bfr[4];
      #pragma unroll
      for (int mi = 0; mi < 4; mi++)
        af[mi] = *reinterpret_cast<const bf16x8*>(&Al[(wm + mi * 16 + (lane & 15)) * 64 + ko]);
      #pragma unroll
      for (int ni = 0; ni < 4; ni++)
        bfr[ni] = *reinterpret_cast<const bf16x8*>(&Bl[(wn + ni * 16 + (lane & 15)) * 64 + ko]);
      #pragma unroll
      for (int mi = 0; mi < 4; mi++)
        #pragma unroll
        for (int ni = 0; ni < 4; ni++)
          acc[mi][ni] = __builtin_amdgcn_mfma_f32_16x16x32_bf16(af[mi], bfr[ni], acc[mi][ni], 0, 0, 0);
    }
  }
  // C/D layout: col = lane&15, row = (lane>>4)*4 + reg
  int col0 = bn * 128 + wn + (lane & 15);
  float bv[4];
  #pragma unroll
  for (int ni = 0; ni < 4; ni++) bv[ni] = bias[col0 + ni * 16];
  int rbase = bm * 128 + wm + (lane >> 4) * 4;
  #pragma unroll
  for (int mi = 0; mi < 4; mi++){
    #pragma unroll
    for (int r = 0; r < 4; r++){
      int m = rbase + mi * 16 + r;
      #pragma unroll
      for (int ni = 0; ni < 4; ni++){
        float v = acc[mi][ni][r] + bv[ni];
        int n = col0 + ni * 16;
        if (EPI == 0){
          outb[(size_t)m * Nout + n] = f2bf(v);
        } else if (EPI == 1){
          v = 0.5f * v * (1.f + erff(v * 0.70710678118654752f));
          outb[(size_t)m * Nout + n] = f2bf(v);
        } else if (EPI == 2){
          size_t idx = (size_t)((m & ~(N_-1)) | ((m + shift) & (N_-1))) * Nout + n;
          outf[idx] = v + resid[idx];     // same-element read->write: safe if aliased
        } else {
          size_t idx = (size_t)m * Nout + n;
          outf[idx] = v + resid[idx];
        }
      }
    }
  }
}

// ---------------- windowed attention (one block/window-group, one wave/head) -------
// qkv row-major [rows][768]: q at col h*32+d, k at 256+h*32+d, v at 512+h*32+d.
// LDS rows padded to 36 floats (144B, 16B-aligned) so K/V inner loops read float4.
__global__ __launch_bounds__(512) void attn_kernel(const u16* __restrict__ qkv,
    const float* __restrict__ rb, u16* __restrict__ o, int shifted)
{
  __shared__ float q_s[H_][WSZ][36];
  __shared__ float k_s[H_][WSZ][36];
  __shared__ float v_s[H_][WSZ][36];
  __shared__ float p_s[H_][WSZ][17];
  int h = threadIdx.x >> 6, lane = threadIdx.x & 63;
  int i = lane >> 2, c8 = (lane & 3) * 8;
  int m0 = blockIdx.x * WSZ;
  size_t base = (size_t)(m0 + i) * 768 + h * HD + c8;
  uint4 rq = *reinterpret_cast<const uint4*>(qkv + base);
  uint4 rk = *reinterpret_cast<const uint4*>(qkv + base + 256);
  uint4 rv = *reinterpret_cast<const uint4*>(qkv + base + 512);
  unpack8(rq, &q_s[h][i][c8]);
  unpack8(rk, &k_s[h][i][c8]);
  unpack8(rv, &v_s[h][i][c8]);
  __syncthreads();

  float qv[HD];
  #pragma unroll
  for (int d4 = 0; d4 < 8; d4++){
    float4 t = *reinterpret_cast<const float4*>(&q_s[h][i][d4 * 4]);
    qv[d4*4+0] = t.x; qv[d4*4+1] = t.y; qv[d4*4+2] = t.z; qv[d4*4+3] = t.w;
  }

  int j0 = (lane & 3) * 4;
  bool lastw = shifted && ((blockIdx.x & (NW - 1)) == NW - 1);
  float p[4];
  #pragma unroll
  for (int jj = 0; jj < 4; jj++){
    int j = j0 + jj;
    float d = 0.f;
    #pragma unroll
    for (int d4 = 0; d4 < 8; d4++){
      float4 kv = *reinterpret_cast<const float4*>(&k_s[h][j][d4 * 4]);
      d += qv[d4*4+0]*kv.x + qv[d4*4+1]*kv.y + qv[d4*4+2]*kv.z + qv[d4*4+3]*kv.w;
    }
    d *= 0.17677669529663689f;          // HD^-0.5
    d += rb[(15 + i - j) * H_ + h];     // relative position bias
    if (lastw && ((i < 8) != (j < 8))) d -= 100.f;  // swin shift mask (window 7)
    p[jj] = d;
  }
  float mx = fmaxf(fmaxf(p[0], p[1]), fmaxf(p[2], p[3]));
  mx = fmaxf(mx, __shfl_xor(mx, 1));
  mx = fmaxf(mx, __shfl_xor(mx, 2));
  float sum = 0.f;
  #pragma unroll
  for (int jj = 0; jj < 4; jj++){ p[jj] = expf(p[jj] - mx); sum += p[jj]; }
  sum += __shfl_xor(sum, 1);
  sum += __shfl_xor(sum, 2);
  float inv = 1.f / sum;
  #pragma unroll
  for (int jj = 0; jj < 4; jj++) p_s[h][i][j0 + jj] = p[jj] * inv;
  __syncthreads();

  float4 a0 = {0.f,0.f,0.f,0.f}, a1 = {0.f,0.f,0.f,0.f};
  #pragma unroll
  for (int j = 0; j < WSZ; j++){
    float pv = p_s[h][i][j];
    float4 v0 = *reinterpret_cast<const float4*>(&v_s[h][j][c8]);
    float4 v1 = *reinterpret_cast<const float4*>(&v_s[h][j][c8 + 4]);
    a0.x += pv*v0.x; a0.y += pv*v0.y; a0.z += pv*v0.z; a0.w += pv*v0.w;
    a1.x += pv*v1.x; a1.y += pv*v1.y; a1.z += pv*v1.z; a1.w += pv*v1.w;
  }
  uint4 w;
  w.x = (u32)f2bf(a0.x) | ((u32)f2bf(a0.y) << 16);
  w.y = (u32)f2bf(a0.z) | ((u32)f2bf(a0.w) << 16);
  w.z = (u32)f2bf(a1.x) | ((u32)f2bf(a1.y) << 16);
  w.w = (u32)f2bf(a1.z) | ((u32)f2bf(a1.w) << 16);
  *reinterpret_cast<uint4*>(o + (size_t)(m0 + i) * C_ + h * HD + c8) = w;
}

// ---------------- launch ----------------
// ws_size = 256 MiB. Layout (peak 164 MB):
//   [0,3M)      bf16 weights
//   [4,36M)     h / h2 bf16 (65536x256)
//   [36,132M)   qkv bf16 (65536x768)   } u (65536x1024, 128MB) reuses [36,164M)
//   [132,164M)  attn-out bf16          }   after o is dead
extern "C" void kernel_launch(void* const* d_in, const int* in_sizes, int n_in,
                              void* d_out, int out_size, void* d_ws, size_t ws_size,
                              hipStream_t stream)
{
  const float* x      = (const float*)d_in[0];
  const float* ln1_g  = (const float*)d_in[1];
  const float* ln1_b  = (const float*)d_in[2];
  const float* qkv_w  = (const float*)d_in[3];
  const float* qkv_b  = (const float*)d_in[4];
  const float* proj_w = (const float*)d_in[5];
  const float* proj_b = (const float*)d_in[6];
  const float* rel_b  = (const float*)d_in[7];
  const float* ln2_g  = (const float*)d_in[8];
  const float* ln2_b  = (const float*)d_in[9];
  const float* fc1_w  = (const float*)d_in[10];
  const float* fc1_b  = (const float*)d_in[11];
  const float* fc2_w  = (const float*)d_in[12];
  const float* fc2_b  = (const float*)d_in[13];
  float* out = (float*)d_out;
  char*  ws  = (char*)d_ws;

  u16* qkv_wb  = (u16*)ws;                 // 393216 elems
  u16* proj_wb = qkv_wb + 393216;          // 131072
  u16* fc1_wb  = proj_wb + 131072;         // 524288
  u16* fc2_wb  = fc1_wb + 524288;          // 524288  (ends at 3 MB)
  u16* h_buf   = (u16*)(ws + (  4ull << 20));
  u16* qkv_buf = (u16*)(ws + ( 36ull << 20));
  u16* o_buf   = (u16*)(ws + (132ull << 20));
  u16* h2_buf  = h_buf;
  u16* u_buf   = qkv_buf;

  cvt_kernel<<<384, 256, 0, stream>>>(qkv_w,  qkv_wb,  393216 / 4);
  cvt_kernel<<<128, 256, 0, stream>>>(proj_w, proj_wb, 131072 / 4);
  cvt_kernel<<<512, 256, 0, stream>>>(fc1_w,  fc1_wb,  524288 / 4);
  cvt_kernel<<<512, 256, 0, stream>>>(fc2_w,  fc2_wb,  524288 / 4);

  const float* xin = x;
  for (int d = 0; d < 2; d++){
    int shift = d ? (WSZ / 2) : 0;
    // LN1 + roll(-shift) -> h (bf16)
    ln_kernel<<<M_TOT / 4, 256, 0, stream>>>(xin, ln1_g + d * C_, ln1_b + d * C_,
        h_buf, shift);
    // QKV: 65536x256 @ (768x256)^T
    gemm_kernel<0, 256, 6><<<512 * 6, 256, 0, stream>>>(h_buf, qkv_wb + d * 196608,
        qkv_b + d * 768, qkv_buf, nullptr, nullptr, 768, 0);
    // windowed attention -> o (bf16, rolled order)
    attn_kernel<<<M_TOT / WSZ, 512, 0, stream>>>(qkv_buf, rel_b + d * 248, o_buf,
        shift ? 1 : 0);
    // proj + roll(+shift) + residual -> x1 (d_out, fp32)
    gemm_kernel<2, 256, 2><<<512 * 2, 256, 0, stream>>>(o_buf, proj_wb + d * 65536,
        proj_b + d * C_, nullptr, out, xin, C_, shift);
    // LN2 -> h2 (bf16)
    ln_kernel<<<M_TOT / 4, 256, 0, stream>>>(out, ln2_g + d * C_, ln2_b + d * C_,
        h2_buf, 0);
    // FC1 + GELU -> u (bf16)
    gemm_kernel<1, 256, 8><<<512 * 8, 256, 0, stream>>>(h2_buf, fc1_wb + d * 262144,
        fc1_b + d * 1024, u_buf, nullptr, nullptr, 1024, 0);
    // FC2 + residual -> d_out (fp32)
    gemm_kernel<3, 1024, 2><<<512 * 2, 256, 0, stream>>>(u_buf, fc2_wb + d * 262144,
        fc2_b + d * C_, nullptr, out, out, C_, 0);
    xin = out;
  }
}